// Round 12
// baseline (150.254 us; speedup 1.0000x reference)
//
#include <hip/hip_runtime.h>

typedef __bf16 v8bf __attribute__((ext_vector_type(8)));
typedef float v4f __attribute__((ext_vector_type(4)));
typedef unsigned int v4u __attribute__((ext_vector_type(4)));
typedef unsigned int v2u __attribute__((ext_vector_type(2)));
typedef unsigned short u16;

#define DEVI static __device__ __forceinline__

DEVI float bf2f(u16 u) {
    union { float f; unsigned int i; } c; c.i = ((unsigned int)u) << 16; return c.f;
}
DEVI u16 f2bf(float f) {
    union { __bf16 b; u16 u; } c; c.b = (__bf16)f;   // native HW cvt, RNE
    return c.u;
}

union Frag { v4u u; v8bf v; u16 h[8]; };

#define GLD16(gptr, lptr) __builtin_amdgcn_global_load_lds( \
    (const __attribute__((address_space(1))) void*)(gptr),  \
    (__attribute__((address_space(3))) void*)(lptr), 16, 0, 0)

// raw barrier + counted waits (no __syncthreads: it drains vmcnt(0) and
// kills in-flight prefetch).  "memory" clobber pins ordering.
#define BAR_VM4()  asm volatile("s_waitcnt vmcnt(4)\ns_barrier" ::: "memory")
#define BAR_VM0()  asm volatile("s_waitcnt vmcnt(0)\ns_barrier" ::: "memory")
#define BAR_LGKM() asm volatile("s_waitcnt lgkmcnt(0)\ns_barrier" ::: "memory")

// ---------------------------------------------------------------------------
// fp32 -> bf16 convert (x, Wq, Wk, Wv packed, Wo) + gate precompute (seg 5):
// gates[token*4+g] = 3*sigmoid(x[token,0:12] . Wg[g])
// ---------------------------------------------------------------------------
__global__ __launch_bounds__(256) void convert6(
    const float* __restrict__ x, const float* __restrict__ wq,
    const float* __restrict__ wk, const float* __restrict__ wv,
    const float* __restrict__ wo, const float* __restrict__ Wg,
    u16* __restrict__ xb, u16* __restrict__ wb, u16* __restrict__ wob,
    float* __restrict__ gates)
{
    if (blockIdx.y == 5) {
        const int stride = gridDim.x * 256;
        for (int i = blockIdx.x * 256 + threadIdx.x; i < 4096 * 4; i += stride) {
            const int token = i >> 2, g = i & 3;
            float dot = 0.f;
#pragma unroll
            for (int c = 0; c < 12; c++)
                dot += x[token * 1024 + c] * Wg[g * 12 + c];
            gates[i] = 3.f / (1.f + __expf(-dot));
        }
        return;
    }
    const float* src; u16* dst; int n;
    switch (blockIdx.y) {
        case 0: src = x;  dst = xb;               n = 4096 * 1024; break;
        case 1: src = wq; dst = wb;               n = 1024 * 1024; break;
        case 2: src = wk; dst = wb + 1024 * 1024; n = 256 * 1024;  break;
        case 3: src = wv; dst = wb + 1280 * 1024; n = 256 * 1024;  break;
        default: src = wo; dst = wob;             n = 1024 * 1024; break;
    }
    const int stride = gridDim.x * 256 * 4;
    for (int i = (blockIdx.x * 256 + threadIdx.x) * 4; i < n; i += stride) {
        const float4 f = *(const float4*)(src + i);
        v2u p;
        p[0] = (unsigned int)f2bf(f.x) | ((unsigned int)f2bf(f.y) << 16);
        p[1] = (unsigned int)f2bf(f.z) | ((unsigned int)f2bf(f.w) << 16);
        *(v2u*)(dst + i) = p;
    }
}

// ---------------------------------------------------------------------------
// QKV GEMM v4: 64x64 tile -> grid (64,24) = 1536 blocks, 32 KB LDS ->
// 5 blocks/CU resident = 20 waves/CU (was 64x128 @ 3/CU = 12 waves/CU).
// 4 waves, each wave 16 rows x FULL 64-col head (1x4 frags) — RoPE pairing
// preserved with the mi dimension dropped.  BK=64 dbuf, counted vmcnt(4),
// both-sides XOR swizzle (source chunk ^= row&7; read = (ks*4+quad)^(l15&7);
// wave row base w*16 == 0 mod 8 so the XOR term stays lane-invariant).
// blockIdx.y: 0-15 = Q head y, 16-19 = K head y-16, 20-23 = V group y-20.
// Fused epilogue:  Q/K: RoPE + RMS-norm *1.2    V: +gate*ve, transposed->vt
// ---------------------------------------------------------------------------
__global__ __launch_bounds__(256) void gemm_qkv(
    const u16* __restrict__ A, const u16* __restrict__ B,
    const float* __restrict__ cs, const float* __restrict__ sn,
    const float* __restrict__ gates, const float* __restrict__ ve,
    u16* __restrict__ qn, u16* __restrict__ kn, u16* __restrict__ vt)
{
    __shared__ __align__(16) u16 As[2][64 * 64];
    __shared__ __align__(16) u16 Bs[2][64 * 64];
    const int tid  = threadIdx.x;
    const int lane = tid & 63, l15 = lane & 15, quad = (lane >> 4) & 3;
    const int w    = tid >> 6;
    const int wr   = w * 16;                       // wave row base (0/16/32/48)
    const int m0   = blockIdx.x * 64, n0 = blockIdx.y * 64;

    const int r0 = tid >> 3;                       // 0..31
    const int swc = ((tid & 7) ^ (r0 & 7)) * 8;    // pre-swizzled source chunk
    const u16* ag = A + (m0 + r0) * 1024 + swc;
    const u16* bg = B + (n0 + r0) * 1024 + swc;
    const int lo = r0 * 64 + (tid & 7) * 8;        // physical LDS dest (linear)
    const int rsw = l15 & 7;                       // read-side XOR term

    v4f acc[4];
    const v4f vzero = {0.f, 0.f, 0.f, 0.f};
#pragma unroll
    for (int j = 0; j < 4; j++) acc[j] = vzero;

#define QKV_STAGE(k0, buf) {                                        \
        const u16* a_ = ag + (k0);  const u16* b_ = bg + (k0);      \
        u16* al_ = &As[buf][lo];    u16* bl_ = &Bs[buf][lo];        \
        GLD16(a_,             al_);                                 \
        GLD16(a_ + 32 * 1024, al_ + 32 * 64);                       \
        GLD16(b_,             bl_);                                 \
        GLD16(b_ + 32 * 1024, bl_ + 32 * 64);                       \
    }

    QKV_STAGE(0, 0);
    for (int t = 0; t < 16; ++t) {
        if (t < 15) {
            QKV_STAGE((t + 1) * 64, (t + 1) & 1);
            BAR_VM4();              // tile t's 4 loads landed; t+1 in flight
        } else {
            BAR_VM0();
        }
        const u16* Asb = As[t & 1];
        const u16* Bsb = Bs[t & 1];
#pragma unroll
        for (int ks = 0; ks < 2; ks++) {
            const int pc = ((ks * 4 + quad) ^ rsw) * 8;   // swizzled read chunk
            v8bf af = *(const v8bf*)&Asb[(wr + l15) * 64 + pc];
#pragma unroll
            for (int ni = 0; ni < 4; ni++) {
                v8bf bv = *(const v8bf*)&Bsb[(ni * 16 + l15) * 64 + pc];
                acc[ni] = __builtin_amdgcn_mfma_f32_16x16x32_bf16(af, bv, acc[ni], 0, 0, 0);
            }
        }
        BAR_LGKM();                 // all reads of buf[t&1] retired
    }
#undef QKV_STAGE

    // ---- fused QKV epilogue (wave owns 16 tokens x one full head) ----
    const int hcol = n0;
    if (hcol < 1280) {                 // Q or K head: RoPE + RMS-norm
        const bool isQ = (hcol < 1024);
        u16* dst = isQ ? (qn + (hcol >> 6) * 64) : (kn + ((hcol - 1024) >> 6) * 64);
        const int dstride = isQ ? 1024 : 256;
#pragma unroll
        for (int r = 0; r < 4; r++) {
            const int row = m0 + wr + quad * 4 + r;
            const int pos = row & 1023;
            const float c0_ = cs[pos * 32 + l15],      s0_ = sn[pos * 32 + l15];
            const float c1_ = cs[pos * 32 + 16 + l15], s1_ = sn[pos * 32 + 16 + l15];
            const float y0 = acc[0][r] * c0_ + acc[2][r] * s0_;
            const float y2 = acc[2][r] * c0_ - acc[0][r] * s0_;
            const float y1 = acc[1][r] * c1_ + acc[3][r] * s1_;
            const float y3 = acc[3][r] * c1_ - acc[1][r] * s1_;
            float ss = y0 * y0 + y1 * y1 + y2 * y2 + y3 * y3;
#pragma unroll
            for (int off = 8; off >= 1; off >>= 1)
                ss += __shfl_xor(ss, off, 64);
            const float inv = rsqrtf(ss * (1.0f / 64.0f) + 1.1920929e-7f) * 1.2f;
            u16* d = dst + row * dstride;
            d[l15]      = f2bf(y0 * inv);
            d[16 + l15] = f2bf(y1 * inv);
            d[32 + l15] = f2bf(y2 * inv);
            d[48 + l15] = f2bf(y3 * inv);
        }
    } else {                           // V head: + gate * ve, transposed store
        const int g = (hcol - 1280) >> 6;
        const int row0 = m0 + wr + quad * 4;     // rows row0..row0+3
        const int b_ = row0 >> 10, t_ = row0 & 1023;
        float gate[4];
#pragma unroll
        for (int r = 0; r < 4; r++) gate[r] = gates[(row0 + r) * 4 + g];
#pragma unroll
        for (int ni = 0; ni < 4; ni++) {
            const int d = ni * 16 + l15;
            union { u16 h[4]; v2u u; } pk;
#pragma unroll
            for (int r = 0; r < 4; r++)
                pk.h[r] = f2bf(acc[ni][r] + gate[r] * ve[(row0 + r) * 256 + g * 64 + d]);
            // t_ is a multiple of 4 -> 8B-aligned store
            *(v2u*)&vt[((b_ * 4 + g) * 64 + d) * 1024 + t_] = pk.u;
        }
    }
}

// ---------------------------------------------------------------------------
// Output projection GEMM v3 (r11 best): 64x64 tile, grid (64,16) = 1024
// blocks = 4 blocks/CU.  4 waves x 32x32 output (2x2 frags), BK=64 dbuf,
// counted vmcnt(4), both-sides XOR swizzle.  Plain fp32 store.
// ---------------------------------------------------------------------------
__global__ __launch_bounds__(256) void gemm_out(
    const u16* __restrict__ A, const u16* __restrict__ B,
    float* __restrict__ C, int N)
{
    __shared__ __align__(16) u16 As[2][64 * 64];
    __shared__ __align__(16) u16 Bs[2][64 * 64];
    const int tid  = threadIdx.x;
    const int lane = tid & 63, l15 = lane & 15, quad = (lane >> 4) & 3;
    const int w    = tid >> 6;
    const int wr   = (w >> 1) * 32, wc = (w & 1) * 32;
    const int m0   = blockIdx.x * 64, n0 = blockIdx.y * 64;

    const int r0 = tid >> 3;
    const int swc = ((tid & 7) ^ (r0 & 7)) * 8;    // pre-swizzled source chunk
    const u16* ag = A + (m0 + r0) * 1024 + swc;
    const u16* bg = B + (n0 + r0) * 1024 + swc;
    const int lo = r0 * 64 + (tid & 7) * 8;        // physical LDS dest (linear)
    const int rsw = l15 & 7;

    v4f acc[2][2];
    const v4f vzero = {0.f, 0.f, 0.f, 0.f};
#pragma unroll
    for (int i = 0; i < 2; i++)
#pragma unroll
        for (int j = 0; j < 2; j++) acc[i][j] = vzero;

#define OUT_STAGE(k0, buf) {                                        \
        const u16* a_ = ag + (k0);  const u16* b_ = bg + (k0);      \
        u16* al_ = &As[buf][lo];    u16* bl_ = &Bs[buf][lo];        \
        GLD16(a_,             al_);                                 \
        GLD16(a_ + 32 * 1024, al_ + 32 * 64);                       \
        GLD16(b_,             bl_);                                 \
        GLD16(b_ + 32 * 1024, bl_ + 32 * 64);                       \
    }

    OUT_STAGE(0, 0);
    for (int t = 0; t < 16; ++t) {
        if (t < 15) {
            OUT_STAGE((t + 1) * 64, (t + 1) & 1);
            BAR_VM4();              // tile t's 4 loads landed; t+1 in flight
        } else {
            BAR_VM0();
        }
        const u16* Asb = As[t & 1];
        const u16* Bsb = Bs[t & 1];
#pragma unroll
        for (int ks = 0; ks < 2; ks++) {
            const int pc = ((ks * 4 + quad) ^ rsw) * 8;
            v8bf af[2], bv[2];
#pragma unroll
            for (int mi = 0; mi < 2; mi++)
                af[mi] = *(const v8bf*)&Asb[(wr + mi * 16 + l15) * 64 + pc];
#pragma unroll
            for (int ni = 0; ni < 2; ni++)
                bv[ni] = *(const v8bf*)&Bsb[(wc + ni * 16 + l15) * 64 + pc];
#pragma unroll
            for (int ni = 0; ni < 2; ni++)
#pragma unroll
                for (int mi = 0; mi < 2; mi++)
                    acc[mi][ni] = __builtin_amdgcn_mfma_f32_16x16x32_bf16(af[mi], bv[ni], acc[mi][ni], 0, 0, 0);
        }
        BAR_LGKM();
    }
#undef OUT_STAGE

#pragma unroll
    for (int mi = 0; mi < 2; mi++) {
        const int row = m0 + wr + mi * 16 + quad * 4;
#pragma unroll
        for (int ni = 0; ni < 2; ni++) {
            const int col = n0 + wc + ni * 16 + l15;
#pragma unroll
            for (int r = 0; r < 4; r++)
                C[(row + r) * N + col] = acc[mi][ni][r];
        }
    }
}

// ---------------------------------------------------------------------------
// Sliding-window flash attention v8 (r4/r9/r10/r11 known-good).  QBLK=64 +
// T14 async-stage split; K/V tile t+1 prefetched into registers before
// compute(t).  Single-buffered LDS (27.6 KB) -> 4 blocks/CU.  72-padding
// already de-conflicts.  Fixed-max softmax with base-2 exp: Q pre-scaled by
// 0.125*log2(e); p = exp2(a - 12*log2e) is a single v_exp_f32.
// ---------------------------------------------------------------------------
__global__ __launch_bounds__(256) void attn(
    const u16* __restrict__ qn, const u16* __restrict__ kn,
    const u16* __restrict__ vt, u16* __restrict__ yo)
{
    __shared__ __align__(16) u16 Ks[64 * 72];
    __shared__ __align__(16) u16 VTs[64 * 72];
    __shared__ __align__(16) u16 Ps[4][16 * 72];
    const int tid  = threadIdx.x;
    const int w    = tid >> 6, lane = tid & 63, l15 = lane & 15, quad = (lane >> 4) & 3;
    const int qb   = blockIdx.x, h = blockIdx.y, b = blockIdx.z;
    const int g    = h >> 2;
    const int qbase = qb * 64;
    const int qabs0 = qbase + w * 16;     // this wave's 16 q-rows
    const int tok0  = b * 1024 + qabs0;
    u16* pw = Ps[w];

    v8bf qf[2];
#pragma unroll
    for (int ks = 0; ks < 2; ks++) {
        Frag f;
        f.u = *(const v4u*)&qn[(tok0 + l15) * 1024 + h * 64 + ks * 32 + quad * 8];
#pragma unroll
        for (int j = 0; j < 8; j++) f.h[j] = f2bf(0.18033688f * bf2f(f.h[j]));  // 0.125*log2e
        qf[ks] = f.v;
    }

    v4f o[4];
    float li[4];
    const v4f vzero = {0.f, 0.f, 0.f, 0.f};
#pragma unroll
    for (int nd = 0; nd < 4; nd++) o[nd] = vzero;
#pragma unroll
    for (int r = 0; r < 4; r++) li[r] = 0.f;

    const int row = tid >> 2, ch = (tid & 3) * 16;
    const int kstart = (qbase >= 256) ? qbase - 256 : 0;
    const int kend   = qbase;          // tile [kend, kend+63] covers q-row qbase+63

    // prefetch registers (named, compile-time indexed — rule #20)
    v4u ka, kb, va, vb;
#define LOADKV(kb_)  {                                                        \
        const int goff_ = (b * 1024 + (kb_) + row) * 256 + g * 64 + ch;       \
        ka = *(const v4u*)&kn[goff_];                                         \
        kb = *(const v4u*)&kn[goff_ + 8];                                     \
        const u16* vs_ = vt + ((b * 4 + g) * 64 + row) * 1024 + (kb_) + ch;   \
        va = *(const v4u*)vs_;                                                \
        vb = *(const v4u*)(vs_ + 8);                                          \
    }

    LOADKV(kstart);
    for (int kbase = kstart; kbase <= kend; kbase += 64) {
        // write current tile (compiler inserts the vmcnt wait on ka..vb)
        *(v4u*)&Ks[row * 72 + ch]      = ka;
        *(v4u*)&Ks[row * 72 + ch + 8]  = kb;
        *(v4u*)&VTs[row * 72 + ch]     = va;
        *(v4u*)&VTs[row * 72 + ch + 8] = vb;
        if (kbase + 64 <= kend) LOADKV(kbase + 64);   // prefetch next (uniform branch)
        BAR_LGKM();                                    // LDS writes visible

        bool skip2[4], full2[4];
#pragma unroll
        for (int ni = 0; ni < 4; ni++) {
            const int left = kbase + ni * 16;
            skip2[ni] = (left > qabs0 + 15) || (qabs0 - (left + 15) > 256);
            full2[ni] = ((left + 15) <= qabs0) && ((qabs0 + 15 - left) <= 256);
        }

#pragma unroll
        for (int ni = 0; ni < 4; ni++) {
            if (skip2[ni]) {
#pragma unroll
                for (int r = 0; r < 4; r++)
                    pw[(quad * 4 + r) * 72 + ni * 16 + l15] = 0;
                continue;
            }
            v8bf kf0 = *(const v8bf*)&Ks[(ni * 16 + l15) * 72 + quad * 8];
            v8bf kf1 = *(const v8bf*)&Ks[(ni * 16 + l15) * 72 + 32 + quad * 8];
            v4f a = vzero;
            a = __builtin_amdgcn_mfma_f32_16x16x32_bf16(qf[0], kf0, a, 0, 0, 0);
            a = __builtin_amdgcn_mfma_f32_16x16x32_bf16(qf[1], kf1, a, 0, 0, 0);
            if (!full2[ni]) {
                const int kj = kbase + ni * 16 + l15;
#pragma unroll
                for (int r = 0; r < 4; r++) {
                    const int qi = qabs0 + quad * 4 + r;
                    if (!((kj <= qi) && (qi - kj <= 256))) a[r] = -1e30f;
                }
            }
#pragma unroll
            for (int r = 0; r < 4; r++) {
                const float p = exp2f(a[r] - 17.312340f);   // 12*log2e
                li[r] += p;
                pw[(quad * 4 + r) * 72 + ni * 16 + l15] = f2bf(p);
            }
        }

#pragma unroll
        for (int ks = 0; ks < 2; ks++) {
            if (skip2[2 * ks] && skip2[2 * ks + 1]) continue;
            v8bf af = *(const v8bf*)&pw[l15 * 72 + ks * 32 + quad * 8];
#pragma unroll
            for (int nd = 0; nd < 4; nd++) {
                v8bf bv = *(const v8bf*)&VTs[(nd * 16 + l15) * 72 + ks * 32 + quad * 8];
                o[nd] = __builtin_amdgcn_mfma_f32_16x16x32_bf16(af, bv, o[nd], 0, 0, 0);
            }
        }
        BAR_LGKM();                                    // reads retired before next ds_write
    }
#undef LOADKV

#pragma unroll
    for (int off = 8; off >= 1; off >>= 1)
#pragma unroll
        for (int r = 0; r < 4; r++)
            li[r] += __shfl_xor(li[r], off, 64);
    float inv[4];
#pragma unroll
    for (int r = 0; r < 4; r++) inv[r] = 1.f / li[r];
#pragma unroll
    for (int nd = 0; nd < 4; nd++) {
        const int col = h * 64 + nd * 16 + l15;
#pragma unroll
        for (int r = 0; r < 4; r++) {
            const int row2 = tok0 + quad * 4 + r;
            yo[row2 * 1024 + col] = f2bf(o[nd][r] * inv[r]);
        }
    }
}

// ---------------------------------------------------------------------------
extern "C" void kernel_launch(void* const* d_in, const int* in_sizes, int n_in,
                              void* d_out, int out_size, void* d_ws, size_t ws_size,
                              hipStream_t stream)
{
    const float* x  = (const float*)d_in[0];
    const float* ve = (const float*)d_in[1];
    const float* cs = (const float*)d_in[2];
    const float* sn = (const float*)d_in[3];
    const float* Wq = (const float*)d_in[4];
    const float* Wk = (const float*)d_in[5];
    const float* Wv = (const float*)d_in[6];
    const float* Wo = (const float*)d_in[7];
    const float* Wg = (const float*)d_in[8];
    // d_in[9] = window_size (fixed 256, hard-coded)

    u16*   xb    = (u16*)d_ws;                 // 4096 x 1024
    u16*   wb    = xb  + 4096 * 1024;          // 1536 x 1024  [Wq;Wk;Wv]
    u16*   wob   = wb  + 1536 * 1024;          // 1024 x 1024  Wo
    u16*   qn    = wob + 1024 * 1024;          // 4096 x 1024
    u16*   kn    = qn  + 4096 * 1024;          // 4096 x 256
    u16*   vt    = kn  + 4096 * 256;           // [4][4][64][1024] transposed V
    u16*   ay    = vt  + 4096 * 256;           // 4096 x 1024 attention out
    float* gates = (float*)(ay + 4096 * 1024); // 4096 x 4

    convert6<<<dim3(512, 6), 256, 0, stream>>>(x, Wq, Wk, Wv, Wo, Wg, xb, wb, wob, gates);
    gemm_qkv<<<dim3(64, 24), 256, 0, stream>>>(xb, wb, cs, sn, gates, ve, qn, kn, vt);
    attn<<<dim3(16, 16, 4), 256, 0, stream>>>(qn, kn, vt, ay);
    gemm_out<<<dim3(64, 16), 256, 0, stream>>>(ay, wob, (float*)d_out, 1024);
}

// Round 14
// 141.309 us; speedup vs baseline: 1.0633x; 1.0633x over previous
//
#include <hip/hip_runtime.h>

typedef __bf16 v8bf __attribute__((ext_vector_type(8)));
typedef float v4f __attribute__((ext_vector_type(4)));
typedef unsigned int v4u __attribute__((ext_vector_type(4)));
typedef unsigned int v2u __attribute__((ext_vector_type(2)));
typedef unsigned short u16;

#define DEVI static __device__ __forceinline__

DEVI float bf2f(u16 u) {
    union { float f; unsigned int i; } c; c.i = ((unsigned int)u) << 16; return c.f;
}
DEVI u16 f2bf(float f) {
    union { __bf16 b; u16 u; } c; c.b = (__bf16)f;   // native HW cvt, RNE
    return c.u;
}

union Frag { v4u u; v8bf v; u16 h[8]; };

#define GLD16(gptr, lptr) __builtin_amdgcn_global_load_lds( \
    (const __attribute__((address_space(1))) void*)(gptr),  \
    (__attribute__((address_space(3))) void*)(lptr), 16, 0, 0)

// raw barrier + counted waits (no __syncthreads: it drains vmcnt(0) and
// kills in-flight prefetch).  "memory" clobber pins ordering.
#define BAR_VM6()  asm volatile("s_waitcnt vmcnt(6)\ns_barrier" ::: "memory")
#define BAR_VM4()  asm volatile("s_waitcnt vmcnt(4)\ns_barrier" ::: "memory")
#define BAR_VM0()  asm volatile("s_waitcnt vmcnt(0)\ns_barrier" ::: "memory")
#define BAR_LGKM() asm volatile("s_waitcnt lgkmcnt(0)\ns_barrier" ::: "memory")

// ---------------------------------------------------------------------------
// fp32 -> bf16 convert (x, Wq, Wk, Wv packed, Wo) + gate precompute (seg 5):
// gates[token*4+g] = 3*sigmoid(x[token,0:12] . Wg[g])
// ---------------------------------------------------------------------------
__global__ __launch_bounds__(256) void convert6(
    const float* __restrict__ x, const float* __restrict__ wq,
    const float* __restrict__ wk, const float* __restrict__ wv,
    const float* __restrict__ wo, const float* __restrict__ Wg,
    u16* __restrict__ xb, u16* __restrict__ wb, u16* __restrict__ wob,
    float* __restrict__ gates)
{
    if (blockIdx.y == 5) {
        const int stride = gridDim.x * 256;
        for (int i = blockIdx.x * 256 + threadIdx.x; i < 4096 * 4; i += stride) {
            const int token = i >> 2, g = i & 3;
            float dot = 0.f;
#pragma unroll
            for (int c = 0; c < 12; c++)
                dot += x[token * 1024 + c] * Wg[g * 12 + c];
            gates[i] = 3.f / (1.f + __expf(-dot));
        }
        return;
    }
    const float* src; u16* dst; int n;
    switch (blockIdx.y) {
        case 0: src = x;  dst = xb;               n = 4096 * 1024; break;
        case 1: src = wq; dst = wb;               n = 1024 * 1024; break;
        case 2: src = wk; dst = wb + 1024 * 1024; n = 256 * 1024;  break;
        case 3: src = wv; dst = wb + 1280 * 1024; n = 256 * 1024;  break;
        default: src = wo; dst = wob;             n = 1024 * 1024; break;
    }
    const int stride = gridDim.x * 256 * 4;
    for (int i = (blockIdx.x * 256 + threadIdx.x) * 4; i < n; i += stride) {
        const float4 f = *(const float4*)(src + i);
        v2u p;
        p[0] = (unsigned int)f2bf(f.x) | ((unsigned int)f2bf(f.y) << 16);
        p[1] = (unsigned int)f2bf(f.z) | ((unsigned int)f2bf(f.w) << 16);
        *(v2u*)(dst + i) = p;
    }
}

// ---------------------------------------------------------------------------
// QKV GEMM v3 (r10/r11 proven best — r12's 64x64 @5/CU regressed +9.7us:
// frag-read:MFMA ratio collapse beat the occupancy gain; optimum bracketed).
// 64x128 tile @ 768 blocks = 3/CU, both-sides LDS XOR-swizzle (source chunk
// ^= row&7; read chunk = (ks*4+quad)^(l15&7)), BK=64 dbuf, counted vmcnt(6).
// Fused epilogue — wave owns 32 tokens x ONE full 64-d head:
//   Q: RoPE + RMS-norm *1.2 -> qn   K: same -> kn
//   V: acc + gates*ve, written TRANSPOSED straight to vt
// ---------------------------------------------------------------------------
__global__ __launch_bounds__(256) void gemm_qkv(
    const u16* __restrict__ A, const u16* __restrict__ B,
    const float* __restrict__ cs, const float* __restrict__ sn,
    const float* __restrict__ gates, const float* __restrict__ ve,
    u16* __restrict__ qn, u16* __restrict__ kn, u16* __restrict__ vt)
{
    __shared__ __align__(16) u16 As[2][64 * 64];
    __shared__ __align__(16) u16 Bs[2][128 * 64];
    const int tid  = threadIdx.x;
    const int lane = tid & 63, l15 = lane & 15, quad = (lane >> 4) & 3;
    const int w    = tid >> 6;
    const int wr   = (w >> 1) * 32, wc = (w & 1) * 64;
    const int m0   = blockIdx.x * 64, n0 = blockIdx.y * 128;

    const int r0 = tid >> 3;                       // 0..31
    const int swc = ((tid & 7) ^ (r0 & 7)) * 8;    // pre-swizzled source chunk
    const u16* ag = A + (m0 + r0) * 1024 + swc;
    const u16* bg = B + (n0 + r0) * 1024 + swc;
    const int lo = r0 * 64 + (tid & 7) * 8;        // physical LDS dest (linear)
    const int rsw = l15 & 7;                       // read-side XOR term

    v4f acc[2][4];
    const v4f vzero = {0.f, 0.f, 0.f, 0.f};
#pragma unroll
    for (int i = 0; i < 2; i++)
#pragma unroll
        for (int j = 0; j < 4; j++) acc[i][j] = vzero;

#define QKV_STAGE(k0, buf) {                                        \
        const u16* a_ = ag + (k0);  const u16* b_ = bg + (k0);      \
        u16* al_ = &As[buf][lo];    u16* bl_ = &Bs[buf][lo];        \
        GLD16(a_,             al_);                                 \
        GLD16(a_ + 32 * 1024, al_ + 32 * 64);                       \
        GLD16(b_,             bl_);                                 \
        GLD16(b_ + 32 * 1024, bl_ + 32 * 64);                       \
        GLD16(b_ + 64 * 1024, bl_ + 64 * 64);                       \
        GLD16(b_ + 96 * 1024, bl_ + 96 * 64);                       \
    }

    QKV_STAGE(0, 0);
    for (int t = 0; t < 16; ++t) {
        if (t < 15) {
            QKV_STAGE((t + 1) * 64, (t + 1) & 1);
            BAR_VM6();              // tile t's 6 loads landed; t+1 in flight
        } else {
            BAR_VM0();
        }
        const u16* Asb = As[t & 1];
        const u16* Bsb = Bs[t & 1];
#pragma unroll
        for (int ks = 0; ks < 2; ks++) {
            const int pc = ((ks * 4 + quad) ^ rsw) * 8;   // swizzled read chunk
            v8bf af[2];
#pragma unroll
            for (int mi = 0; mi < 2; mi++)
                af[mi] = *(const v8bf*)&Asb[(wr + mi * 16 + l15) * 64 + pc];
#pragma unroll
            for (int ni = 0; ni < 4; ni++) {
                v8bf bv = *(const v8bf*)&Bsb[(wc + ni * 16 + l15) * 64 + pc];
#pragma unroll
                for (int mi = 0; mi < 2; mi++)
                    acc[mi][ni] = __builtin_amdgcn_mfma_f32_16x16x32_bf16(af[mi], bv, acc[mi][ni], 0, 0, 0);
            }
        }
        BAR_LGKM();                 // all reads of buf[t&1] retired
    }
#undef QKV_STAGE

    // ---- fused QKV epilogue ----
    const int hcol = n0 + wc;          // start col of this wave's head
    if (hcol < 1280) {                 // Q or K head: RoPE + RMS-norm
        const bool isQ = (hcol < 1024);
        u16* dst = isQ ? (qn + (hcol >> 6) * 64) : (kn + ((hcol - 1024) >> 6) * 64);
        const int dstride = isQ ? 1024 : 256;
#pragma unroll
        for (int mi = 0; mi < 2; mi++) {
#pragma unroll
            for (int r = 0; r < 4; r++) {
                const int row = m0 + wr + mi * 16 + quad * 4 + r;
                const int pos = row & 1023;
                const float c0_ = cs[pos * 32 + l15],      s0_ = sn[pos * 32 + l15];
                const float c1_ = cs[pos * 32 + 16 + l15], s1_ = sn[pos * 32 + 16 + l15];
                const float y0 = acc[mi][0][r] * c0_ + acc[mi][2][r] * s0_;
                const float y2 = acc[mi][2][r] * c0_ - acc[mi][0][r] * s0_;
                const float y1 = acc[mi][1][r] * c1_ + acc[mi][3][r] * s1_;
                const float y3 = acc[mi][3][r] * c1_ - acc[mi][1][r] * s1_;
                float ss = y0 * y0 + y1 * y1 + y2 * y2 + y3 * y3;
#pragma unroll
                for (int off = 8; off >= 1; off >>= 1)
                    ss += __shfl_xor(ss, off, 64);
                const float inv = rsqrtf(ss * (1.0f / 64.0f) + 1.1920929e-7f) * 1.2f;
                u16* d = dst + row * dstride;
                d[l15]      = f2bf(y0 * inv);
                d[16 + l15] = f2bf(y1 * inv);
                d[32 + l15] = f2bf(y2 * inv);
                d[48 + l15] = f2bf(y3 * inv);
            }
        }
    } else {                           // V head: + gate * ve, transposed store
        const int g = (hcol - 1280) >> 6;
#pragma unroll
        for (int mi = 0; mi < 2; mi++) {
            const int row0 = m0 + wr + mi * 16 + quad * 4;   // rows row0..row0+3
            const int b_ = row0 >> 10, t_ = row0 & 1023;     // same b for all 4 r
            float gate[4];
#pragma unroll
            for (int r = 0; r < 4; r++) gate[r] = gates[(row0 + r) * 4 + g];
#pragma unroll
            for (int ni = 0; ni < 4; ni++) {
                const int d = ni * 16 + l15;
                union { u16 h[4]; v2u u; } pk;
#pragma unroll
                for (int r = 0; r < 4; r++)
                    pk.h[r] = f2bf(acc[mi][ni][r] + gate[r] * ve[(row0 + r) * 256 + g * 64 + d]);
                // t_ is a multiple of 4 -> 8B-aligned store
                *(v2u*)&vt[((b_ * 4 + g) * 64 + d) * 1024 + t_] = pk.u;
            }
        }
    }
}

// ---------------------------------------------------------------------------
// Output projection GEMM v3 (r11 best): 64x64 tile, grid (64,16) = 1024
// blocks = 4 blocks/CU.  4 waves x 32x32 output (2x2 frags), BK=64 dbuf,
// counted vmcnt(4), both-sides XOR swizzle.  Plain fp32 store.
// ---------------------------------------------------------------------------
__global__ __launch_bounds__(256) void gemm_out(
    const u16* __restrict__ A, const u16* __restrict__ B,
    float* __restrict__ C, int N)
{
    __shared__ __align__(16) u16 As[2][64 * 64];
    __shared__ __align__(16) u16 Bs[2][64 * 64];
    const int tid  = threadIdx.x;
    const int lane = tid & 63, l15 = lane & 15, quad = (lane >> 4) & 3;
    const int w    = tid >> 6;
    const int wr   = (w >> 1) * 32, wc = (w & 1) * 32;
    const int m0   = blockIdx.x * 64, n0 = blockIdx.y * 64;

    const int r0 = tid >> 3;
    const int swc = ((tid & 7) ^ (r0 & 7)) * 8;    // pre-swizzled source chunk
    const u16* ag = A + (m0 + r0) * 1024 + swc;
    const u16* bg = B + (n0 + r0) * 1024 + swc;
    const int lo = r0 * 64 + (tid & 7) * 8;        // physical LDS dest (linear)
    const int rsw = l15 & 7;

    v4f acc[2][2];
    const v4f vzero = {0.f, 0.f, 0.f, 0.f};
#pragma unroll
    for (int i = 0; i < 2; i++)
#pragma unroll
        for (int j = 0; j < 2; j++) acc[i][j] = vzero;

#define OUT_STAGE(k0, buf) {                                        \
        const u16* a_ = ag + (k0);  const u16* b_ = bg + (k0);      \
        u16* al_ = &As[buf][lo];    u16* bl_ = &Bs[buf][lo];        \
        GLD16(a_,             al_);                                 \
        GLD16(a_ + 32 * 1024, al_ + 32 * 64);                       \
        GLD16(b_,             bl_);                                 \
        GLD16(b_ + 32 * 1024, bl_ + 32 * 64);                       \
    }

    OUT_STAGE(0, 0);
    for (int t = 0; t < 16; ++t) {
        if (t < 15) {
            OUT_STAGE((t + 1) * 64, (t + 1) & 1);
            BAR_VM4();              // tile t's 4 loads landed; t+1 in flight
        } else {
            BAR_VM0();
        }
        const u16* Asb = As[t & 1];
        const u16* Bsb = Bs[t & 1];
#pragma unroll
        for (int ks = 0; ks < 2; ks++) {
            const int pc = ((ks * 4 + quad) ^ rsw) * 8;
            v8bf af[2], bv[2];
#pragma unroll
            for (int mi = 0; mi < 2; mi++)
                af[mi] = *(const v8bf*)&Asb[(wr + mi * 16 + l15) * 64 + pc];
#pragma unroll
            for (int ni = 0; ni < 2; ni++)
                bv[ni] = *(const v8bf*)&Bsb[(wc + ni * 16 + l15) * 64 + pc];
#pragma unroll
            for (int ni = 0; ni < 2; ni++)
#pragma unroll
                for (int mi = 0; mi < 2; mi++)
                    acc[mi][ni] = __builtin_amdgcn_mfma_f32_16x16x32_bf16(af[mi], bv[ni], acc[mi][ni], 0, 0, 0);
        }
        BAR_LGKM();
    }
#undef OUT_STAGE

#pragma unroll
    for (int mi = 0; mi < 2; mi++) {
        const int row = m0 + wr + mi * 16 + quad * 4;
#pragma unroll
        for (int ni = 0; ni < 2; ni++) {
            const int col = n0 + wc + ni * 16 + l15;
#pragma unroll
            for (int r = 0; r < 4; r++)
                C[(row + r) * N + col] = acc[mi][ni][r];
        }
    }
}

// ---------------------------------------------------------------------------
// Sliding-window flash attention v10 = v8 (r4/r9/r10/r11 known-good) + T5
// s_setprio(1) around both MFMA clusters.  Mechanism (m191): 4 independent
// blocks/CU at different phases — scheduler favors MFMA-entering waves over
// waves issuing softmax VALU / staging.  (m190's null was lockstep GEMM;
// GEMMs here stay setprio-free.)
// QBLK=64 + T14 async-stage split; single-buffered LDS (27.6 KB) -> 4
// blocks/CU.  Fixed-max softmax with base-2 exp.
// ---------------------------------------------------------------------------
__global__ __launch_bounds__(256) void attn(
    const u16* __restrict__ qn, const u16* __restrict__ kn,
    const u16* __restrict__ vt, u16* __restrict__ yo)
{
    __shared__ __align__(16) u16 Ks[64 * 72];
    __shared__ __align__(16) u16 VTs[64 * 72];
    __shared__ __align__(16) u16 Ps[4][16 * 72];
    const int tid  = threadIdx.x;
    const int w    = tid >> 6, lane = tid & 63, l15 = lane & 15, quad = (lane >> 4) & 3;
    const int qb   = blockIdx.x, h = blockIdx.y, b = blockIdx.z;
    const int g    = h >> 2;
    const int qbase = qb * 64;
    const int qabs0 = qbase + w * 16;     // this wave's 16 q-rows
    const int tok0  = b * 1024 + qabs0;
    u16* pw = Ps[w];

    v8bf qf[2];
#pragma unroll
    for (int ks = 0; ks < 2; ks++) {
        Frag f;
        f.u = *(const v4u*)&qn[(tok0 + l15) * 1024 + h * 64 + ks * 32 + quad * 8];
#pragma unroll
        for (int j = 0; j < 8; j++) f.h[j] = f2bf(0.18033688f * bf2f(f.h[j]));  // 0.125*log2e
        qf[ks] = f.v;
    }

    v4f o[4];
    float li[4];
    const v4f vzero = {0.f, 0.f, 0.f, 0.f};
#pragma unroll
    for (int nd = 0; nd < 4; nd++) o[nd] = vzero;
#pragma unroll
    for (int r = 0; r < 4; r++) li[r] = 0.f;

    const int row = tid >> 2, ch = (tid & 3) * 16;
    const int kstart = (qbase >= 256) ? qbase - 256 : 0;
    const int kend   = qbase;          // tile [kend, kend+63] covers q-row qbase+63

    // prefetch registers (named, compile-time indexed — rule #20)
    v4u ka, kb, va, vb;
#define LOADKV(kb_)  {                                                        \
        const int goff_ = (b * 1024 + (kb_) + row) * 256 + g * 64 + ch;       \
        ka = *(const v4u*)&kn[goff_];                                         \
        kb = *(const v4u*)&kn[goff_ + 8];                                     \
        const u16* vs_ = vt + ((b * 4 + g) * 64 + row) * 1024 + (kb_) + ch;   \
        va = *(const v4u*)vs_;                                                \
        vb = *(const v4u*)(vs_ + 8);                                          \
    }

    LOADKV(kstart);
    for (int kbase = kstart; kbase <= kend; kbase += 64) {
        // write current tile (compiler inserts the vmcnt wait on ka..vb)
        *(v4u*)&Ks[row * 72 + ch]      = ka;
        *(v4u*)&Ks[row * 72 + ch + 8]  = kb;
        *(v4u*)&VTs[row * 72 + ch]     = va;
        *(v4u*)&VTs[row * 72 + ch + 8] = vb;
        if (kbase + 64 <= kend) LOADKV(kbase + 64);   // prefetch next (uniform branch)
        BAR_LGKM();                                    // LDS writes visible

        bool skip2[4], full2[4];
#pragma unroll
        for (int ni = 0; ni < 4; ni++) {
            const int left = kbase + ni * 16;
            skip2[ni] = (left > qabs0 + 15) || (qabs0 - (left + 15) > 256);
            full2[ni] = ((left + 15) <= qabs0) && ((qabs0 + 15 - left) <= 256);
        }

#pragma unroll
        for (int ni = 0; ni < 4; ni++) {
            if (skip2[ni]) {
#pragma unroll
                for (int r = 0; r < 4; r++)
                    pw[(quad * 4 + r) * 72 + ni * 16 + l15] = 0;
                continue;
            }
            v8bf kf0 = *(const v8bf*)&Ks[(ni * 16 + l15) * 72 + quad * 8];
            v8bf kf1 = *(const v8bf*)&Ks[(ni * 16 + l15) * 72 + 32 + quad * 8];
            v4f a = vzero;
            __builtin_amdgcn_s_setprio(1);
            a = __builtin_amdgcn_mfma_f32_16x16x32_bf16(qf[0], kf0, a, 0, 0, 0);
            a = __builtin_amdgcn_mfma_f32_16x16x32_bf16(qf[1], kf1, a, 0, 0, 0);
            __builtin_amdgcn_s_setprio(0);
            if (!full2[ni]) {
                const int kj = kbase + ni * 16 + l15;
#pragma unroll
                for (int r = 0; r < 4; r++) {
                    const int qi = qabs0 + quad * 4 + r;
                    if (!((kj <= qi) && (qi - kj <= 256))) a[r] = -1e30f;
                }
            }
#pragma unroll
            for (int r = 0; r < 4; r++) {
                const float p = exp2f(a[r] - 17.312340f);   // 12*log2e
                li[r] += p;
                pw[(quad * 4 + r) * 72 + ni * 16 + l15] = f2bf(p);
            }
        }

#pragma unroll
        for (int ks = 0; ks < 2; ks++) {
            if (skip2[2 * ks] && skip2[2 * ks + 1]) continue;
            v8bf af = *(const v8bf*)&pw[l15 * 72 + ks * 32 + quad * 8];
            __builtin_amdgcn_s_setprio(1);
#pragma unroll
            for (int nd = 0; nd < 4; nd++) {
                v8bf bv = *(const v8bf*)&VTs[(nd * 16 + l15) * 72 + ks * 32 + quad * 8];
                o[nd] = __builtin_amdgcn_mfma_f32_16x16x32_bf16(af, bv, o[nd], 0, 0, 0);
            }
            __builtin_amdgcn_s_setprio(0);
        }
        BAR_LGKM();                                    // reads retired before next ds_write
    }
#undef LOADKV

#pragma unroll
    for (int off = 8; off >= 1; off >>= 1)
#pragma unroll
        for (int r = 0; r < 4; r++)
            li[r] += __shfl_xor(li[r], off, 64);
    float inv[4];
#pragma unroll
    for (int r = 0; r < 4; r++) inv[r] = 1.f / li[r];
#pragma unroll
    for (int nd = 0; nd < 4; nd++) {
        const int col = h * 64 + nd * 16 + l15;
#pragma unroll
        for (int r = 0; r < 4; r++) {
            const int row2 = tok0 + quad * 4 + r;
            yo[row2 * 1024 + col] = f2bf(o[nd][r] * inv[r]);
        }
    }
}

// ---------------------------------------------------------------------------
extern "C" void kernel_launch(void* const* d_in, const int* in_sizes, int n_in,
                              void* d_out, int out_size, void* d_ws, size_t ws_size,
                              hipStream_t stream)
{
    const float* x  = (const float*)d_in[0];
    const float* ve = (const float*)d_in[1];
    const float* cs = (const float*)d_in[2];
    const float* sn = (const float*)d_in[3];
    const float* Wq = (const float*)d_in[4];
    const float* Wk = (const float*)d_in[5];
    const float* Wv = (const float*)d_in[6];
    const float* Wo = (const float*)d_in[7];
    const float* Wg = (const float*)d_in[8];
    // d_in[9] = window_size (fixed 256, hard-coded)

    u16*   xb    = (u16*)d_ws;                 // 4096 x 1024
    u16*   wb    = xb  + 4096 * 1024;          // 1536 x 1024  [Wq;Wk;Wv]
    u16*   wob   = wb  + 1536 * 1024;          // 1024 x 1024  Wo
    u16*   qn    = wob + 1024 * 1024;          // 4096 x 1024
    u16*   kn    = qn  + 4096 * 1024;          // 4096 x 256
    u16*   vt    = kn  + 4096 * 256;           // [4][4][64][1024] transposed V
    u16*   ay    = vt  + 4096 * 256;           // 4096 x 1024 attention out
    float* gates = (float*)(ay + 4096 * 1024); // 4096 x 4

    convert6<<<dim3(512, 6), 256, 0, stream>>>(x, Wq, Wk, Wv, Wo, Wg, xb, wb, wob, gates);
    gemm_qkv<<<dim3(64, 12), 256, 0, stream>>>(xb, wb, cs, sn, gates, ve, qn, kn, vt);
    attn<<<dim3(16, 16, 4), 256, 0, stream>>>(qn, kn, vt, ay);
    gemm_out<<<dim3(64, 16), 256, 0, stream>>>(ay, wob, (float*)d_out, 1024);
}